// Round 4
// baseline (255.422 us; speedup 1.0000x reference)
//
#include <hip/hip_runtime.h>
#include <hip/hip_bf16.h>

// TTN Conv: out[n,p,o,site] = sum_{c,i,j,k,l} a_i b_j c_k d_l * W[c,p,site,ijkl,o] + bias
// Per site: GEMM D[n=128][po=48] = sum_{k=768} A[n][k] * W[k][po], bf16 16x16x32 MFMA.
//
// R4 structure (1 block/site, 256 thr = 4 waves):
//  - A-operand never touches LDS: lane (row,quad) holds x-factors for its two
//    MFMA rows; A-frag[j] = a_mb * b_{ij4} * cd8[j], packed with v_cvt_pk_bf16_f32.
//    Per-lane factor state: a4[2][4], b2[2][2], cd8[2][8] (only the quad's slice).
//  - sW double-buffered (2 x 48 x 72 shorts = 13.8 KB): 1 barrier per chunk.
//    W prefetched 2 chunks ahead in regs (3 x float4 per thread).
//  - Epilogue -> ws[site][n*48+po]: each store instr covers 4 full 64B lines.
// Phase 2: tiled transpose ws(961x6144) -> out(6144x961) + bias (proven R2/R3).
//
// harness note: dur_us includes ~117us of 0xAA-poison fills + d_in restore
// (R1: dispatch 598 vs dur 715). Optimizable part = dur_us - ~117.

typedef __attribute__((ext_vector_type(8))) short short8;
typedef __attribute__((ext_vector_type(4))) float floatx4;

#define WS_ELEMS (961u * 6144u)
#define SW_STR 72   // 144 B row stride = 9 granules -> even granule spread on b128 reads

static __device__ __forceinline__ unsigned pkbf(float lo, float hi) {
  __hip_bfloat162 h = __float22bfloat162_rn(make_float2(lo, hi));
  union { __hip_bfloat162 h; unsigned u; } v;
  v.h = h;
  return v.u;   // lo in bits [15:0], hi in [31:16]
}

template <bool TO_WS>
__global__ __launch_bounds__(256, 4)
void ttn_conv_mfma(const float* __restrict__ x,
                   const float* __restrict__ tensors,
                   const float* __restrict__ bias,
                   float* __restrict__ dst) {
  __shared__ __align__(16) unsigned short sW[2][48 * SW_STR];  // 13824 B

  const int site = blockIdx.x;
  const int xx = site / 31, yy = site - xx * 31;
  const int t = threadIdx.x;
  const int lane = t & 63, wave = t >> 6;
  const int row = lane & 15, quad = lane >> 4;

  // sW staging role: thread stages m-pair (2*q_st, 2*q_st+1) for p_st, all 6 o.
  const int p_st = t >> 5, q_st = t & 31;

  floatx4 acc[2][3];
#pragma unroll
  for (int i0 = 0; i0 < 2; ++i0)
#pragma unroll
    for (int j0 = 0; j0 < 3; ++j0)
      acc[i0][j0] = (floatx4){0.f, 0.f, 0.f, 0.f};

  float a4[2][4], b2[2][2], cd8[2][8];
  float4 wv0, wv1, wv2;

  auto loadW = [&](int c, int mb) {
    const float* src = tensors +
        ((size_t)((c * 8 + p_st) * 961 + site)) * 1536 + (size_t)(mb * 64 + 2 * q_st) * 6;
    wv0 = *(const float4*)src;
    wv1 = *(const float4*)(src + 4);
    wv2 = *(const float4*)(src + 8);
  };
  auto storeW = [&](int buf) {
    const float vv[12] = {wv0.x, wv0.y, wv0.z, wv0.w, wv1.x, wv1.y,
                          wv1.z, wv1.w, wv2.x, wv2.y, wv2.z, wv2.w};
#pragma unroll
    for (int o = 0; o < 6; ++o)
      *(unsigned*)&sW[buf][(p_st * 6 + o) * SW_STR + 2 * q_st] = pkbf(vv[o], vv[o + 6]);
  };
  auto loadFactors = [&](int c) {
    // lane slice: ij4 used = {quad>>1, 2+(quad>>1)} (ks=0/1); kl used = (quad&1)*8 + 0..7
#pragma unroll
    for (int mt = 0; mt < 2; ++mt) {
      const int n = wave * 32 + mt * 16 + row;
      const float* xb = x + ((size_t)n * 3 + c) * 4096 + xx * 32 + yy;
      float dq[4];
#pragma unroll
      for (int i = 0; i < 4; ++i) {
        a4[mt][i] = xb[i * 1024];        // a_i = x[n,c,i,xx,yy]
        dq[i]     = xb[i * 1024 + 33];   // d_l = x[n,c,l,xx+1,yy+1]
      }
      b2[mt][0] = xb[(quad >> 1) * 1024 + 32];        // b_{ij4}, ks=0
      b2[mt][1] = xb[(2 + (quad >> 1)) * 1024 + 32];  // b_{ij4}, ks=1
      const float cq0 = xb[(2 * (quad & 1)) * 1024 + 1];
      const float cq1 = xb[(2 * (quad & 1) + 1) * 1024 + 1];
#pragma unroll
      for (int j = 0; j < 8; ++j)
        cd8[mt][j] = (j < 4 ? cq0 : cq1) * dq[j & 3];  // c_{kl>>2} * d_{kl&3}
    }
  };

  loadW(0, 0);
  storeW(0);          // chunk 0 -> buf0 (visible after first barrier)
  loadW(0, 1);        // chunk 1 in regs
  loadFactors(0);

  for (int c = 0; c < 3; ++c) {
    if (c) loadFactors(c);   // prior c's MFMAs already issued (program order)
#pragma unroll
    for (int mb = 0; mb < 4; ++mb) {
      const int ch = c * 4 + mb;
      const int bp = mb & 1;
      __syncthreads();  // buf[bp] (chunk ch) visible; prior reads of buf[1-bp] done

      // ---- compute chunk ch from buf[bp]; A-frags built in registers ----
#pragma unroll
      for (int ks = 0; ks < 2; ++ks) {
        short8 bfr[3];
#pragma unroll
        for (int nt = 0; nt < 3; ++nt)
          bfr[nt] = *(const short8*)&sW[bp][(nt * 16 + row) * SW_STR + ks * 32 + quad * 8];
#pragma unroll
        for (int mt = 0; mt < 2; ++mt) {
          const float ab = a4[mt][mb] * b2[mt][ks];
          union { unsigned u[4]; short8 s; } af;
#pragma unroll
          for (int jj = 0; jj < 4; ++jj)
            af.u[jj] = pkbf(ab * cd8[mt][2 * jj], ab * cd8[mt][2 * jj + 1]);
#pragma unroll
          for (int nt = 0; nt < 3; ++nt)
            acc[mt][nt] = __builtin_amdgcn_mfma_f32_16x16x32_bf16(
                af.s, bfr[nt], acc[mt][nt], 0, 0, 0);
        }
      }

      // ---- stage chunk ch+1 (regs -> buf[1-bp]); prefetch chunk ch+2 ----
      if (ch < 11) storeW(1 - bp);
      if (ch < 10) {
        const int i2 = ch + 2;
        loadW(i2 >> 2, i2 & 3);
      }
    }
  }

  // ---- epilogue: D row = quad*4+r (n-local), col = row (po-local) ----
  if (TO_WS) {
#pragma unroll
    for (int mt = 0; mt < 2; ++mt)
#pragma unroll
      for (int r = 0; r < 4; ++r) {
        const int n = wave * 32 + mt * 16 + quad * 4 + r;
#pragma unroll
        for (int nt = 0; nt < 3; ++nt) {
          const int po = nt * 16 + row;
          dst[(size_t)site * 6144 + n * 48 + po] = acc[mt][nt][r];
        }
      }
  } else {
#pragma unroll
    for (int mt = 0; mt < 2; ++mt)
#pragma unroll
      for (int r = 0; r < 4; ++r) {
        const int n = wave * 32 + mt * 16 + quad * 4 + r;
#pragma unroll
        for (int nt = 0; nt < 3; ++nt) {
          const int po = nt * 16 + row;
          const int p = po / 6, o = po - p * 6;
          dst[(size_t)(n * 48 + po) * 961 + site] =
              acc[mt][nt][r] + bias[(p * 961 + site) * 6 + o];
        }
      }
  }
}

// out[f*961 + site] = ws[site*6144 + f] + bias[(p*961+site)*6 + o],  f = n*48+p*6+o
__global__ __launch_bounds__(256, 8)
void ttn_transpose_bias(const float* __restrict__ ws,
                        const float* __restrict__ bias,
                        float* __restrict__ out) {
  __shared__ float tile[32][33];
  const int f0 = blockIdx.x * 32;
  const int s0 = blockIdx.y * 32;
  const int tx = threadIdx.x;       // 0..31
  const int ty = threadIdx.y;       // 0..7

#pragma unroll
  for (int rr = 0; rr < 4; ++rr) {
    const int srow = ty + rr * 8;
    const int site = s0 + srow;
    if (site < 961)
      tile[srow][tx] = ws[(size_t)site * 6144 + f0 + tx];
  }
  __syncthreads();

#pragma unroll
  for (int rr = 0; rr < 4; ++rr) {
    const int fy = ty + rr * 8;
    const int f = f0 + fy;
    const int site = s0 + tx;
    if (site < 961) {
      const int po = f % 48;
      const int p = po / 6, o = po - p * 6;
      out[(size_t)f * 961 + site] = tile[tx][fy] + bias[(p * 961 + site) * 6 + o];
    }
  }
}

extern "C" void kernel_launch(void* const* d_in, const int* in_sizes, int n_in,
                              void* d_out, int out_size, void* d_ws, size_t ws_size,
                              hipStream_t stream) {
  const float* x       = (const float*)d_in[0];
  const float* tensors = (const float*)d_in[1];
  const float* bias    = (const float*)d_in[2];
  float* out           = (float*)d_out;

  const size_t need = (size_t)WS_ELEMS * sizeof(float);
  if (d_ws != nullptr && ws_size >= need) {
    float* ws = (float*)d_ws;
    hipLaunchKernelGGL((ttn_conv_mfma<true>), dim3(961), dim3(256), 0, stream,
                       x, tensors, bias, ws);
    hipLaunchKernelGGL(ttn_transpose_bias, dim3(192, 31), dim3(32, 8), 0, stream,
                       ws, bias, out);
  } else {
    hipLaunchKernelGGL((ttn_conv_mfma<false>), dim3(961), dim3(256), 0, stream,
                       x, tensors, bias, out);
  }
}

// Round 5
// 245.419 us; speedup vs baseline: 1.0408x; 1.0408x over previous
//
#include <hip/hip_runtime.h>
#include <hip/hip_bf16.h>

// TTN Conv: out[n,p,o,site] = sum_{c,i,j,k,l} a_i b_j c_k d_l * W[c,p,site,ijkl,o] + bias
// Per site: GEMM D[n=128][po=48] = sum_{k=768} A[n][k] * W[k][po], bf16 16x16x32 MFMA.
//
// R5: latency-bound fix (R4 was 91us with ALL pipes idle: loads were issued
// ~50cyc before the barrier whose vmcnt(0) drain then ate full HBM latency x12).
//  - All global loads issued at STAGE TOP, right after the barrier -> lead = full stage.
//  - 2 chunks per stage (K=128): 6 barriers instead of 12.
//  - x-factors loaded as float2 one stage ahead (raw regs), converted at use stage.
//  - A-operand stays register-built (no LDS round-trip); sW double-buffered 26KB.
// Phase 2: tiled transpose ws(961x6144) -> out(6144x961) + bias (proven R2-R4).
//
// harness note: dur_us includes ~117us of 0xAA-poison fills + d_in restore.

typedef __attribute__((ext_vector_type(8))) short short8;
typedef __attribute__((ext_vector_type(4))) float floatx4;

#define WS_ELEMS (961u * 6144u)
#define SW_COLS 136   // 128 + 8 pad; row stride 272B -> bank start 4*row mod 32

static __device__ __forceinline__ unsigned pkbf(float lo, float hi) {
  __hip_bfloat162 h = __float22bfloat162_rn(make_float2(lo, hi));
  union { __hip_bfloat162 h; unsigned u; } v;
  v.h = h;
  return v.u;   // lo in [15:0], hi in [31:16]
}

template <bool TO_WS>
__global__ __launch_bounds__(256, 4)
void ttn_conv_mfma(const float* __restrict__ x,
                   const float* __restrict__ tensors,
                   const float* __restrict__ bias,
                   float* __restrict__ dst) {
  __shared__ __align__(16) unsigned short sW[2][48 * SW_COLS];  // 26112 B

  const int site = blockIdx.x;
  const int xx = site / 31, yy = site - xx * 31;
  const int t = threadIdx.x;
  const int lane = t & 63, wave = t >> 6;
  const int row = lane & 15, quad = lane >> 4;

  // sW staging role: thread (p_st, q_st) stages m-pair (2q_st, 2q_st+1) of each
  // chunk in the pair, for all 6 o of its p.
  const int p_st = t >> 5, q_st = t & 31;

  floatx4 acc[2][3];
#pragma unroll
  for (int i0 = 0; i0 < 2; ++i0)
#pragma unroll
    for (int j0 = 0; j0 < 3; ++j0)
      acc[i0][j0] = (floatx4){0.f, 0.f, 0.f, 0.f};

  float a4[2][4], b2[2][2], cd8[2][8];     // converted factors for current c
  float2 rAC[2][4], rBD[2][4];             // raw (a_i,c_i), (b_i,d_i) for next c
  float4 wv[6];                            // one W pair (128 m x this thread's slice)

  // pair s (s=0..5): chunks 2s,2s+1; c = s>>1; mb = 2*(s&1) + h, h in {0,1}
  auto loadPair = [&](int s) {
    const int c = s >> 1;
    const float* base = tensors + ((size_t)((c * 8 + p_st) * 961 + site)) * 1536;
#pragma unroll
    for (int h = 0; h < 2; ++h) {
      const float* src = base + (size_t)((2 * (s & 1) + h) * 64 + 2 * q_st) * 6;
      wv[h * 3 + 0] = *(const float4*)src;
      wv[h * 3 + 1] = *(const float4*)(src + 4);
      wv[h * 3 + 2] = *(const float4*)(src + 8);
    }
  };
  auto storePair = [&](int buf) {
#pragma unroll
    for (int h = 0; h < 2; ++h) {
      const float4 w0 = wv[h * 3], w1 = wv[h * 3 + 1], w2 = wv[h * 3 + 2];
      const float vv[12] = {w0.x, w0.y, w0.z, w0.w, w1.x, w1.y,
                            w1.z, w1.w, w2.x, w2.y, w2.z, w2.w};
#pragma unroll
      for (int o = 0; o < 6; ++o)
        *(unsigned*)&sW[buf][(p_st * 6 + o) * SW_COLS + h * 64 + 2 * q_st] =
            pkbf(vv[o], vv[o + 6]);
    }
  };
  auto loadRaw = [&](int c) {
#pragma unroll
    for (int mt = 0; mt < 2; ++mt) {
      const int n = wave * 32 + mt * 16 + row;
      const float* xb = x + ((size_t)n * 3 + c) * 4096 + xx * 32 + yy;
#pragma unroll
      for (int i = 0; i < 4; ++i) {
        rAC[mt][i] = *(const float2*)(xb + i * 1024);       // (a_i, c_i)
        rBD[mt][i] = *(const float2*)(xb + i * 1024 + 32);  // (b_i, d_i)
      }
    }
  };
  auto cvtFactors = [&]() {
    const int qh = quad >> 1, ql = quad & 1;
#pragma unroll
    for (int mt = 0; mt < 2; ++mt) {
#pragma unroll
      for (int i = 0; i < 4; ++i) a4[mt][i] = rAC[mt][i].x;
      b2[mt][0] = qh ? rBD[mt][1].x : rBD[mt][0].x;         // b_{ij4}, ks even
      b2[mt][1] = qh ? rBD[mt][3].x : rBD[mt][2].x;         // b_{ij4}, ks odd
      const float cq0 = ql ? rAC[mt][2].y : rAC[mt][0].y;   // c_{kl>>2}
      const float cq1 = ql ? rAC[mt][3].y : rAC[mt][1].y;
#pragma unroll
      for (int j = 0; j < 8; ++j)
        cd8[mt][j] = (j < 4 ? cq0 : cq1) * rBD[mt][j & 3].y;  // c * d_l
    }
  };

  // ---- prologue ----
  loadPair(0);
  loadRaw(0);
  cvtFactors();        // waits on raw
  storePair(0);        // waits on wv
  loadPair(1);         // in flight across first barrier
  __syncthreads();

  // ---- 6 stages of K=128 ----
#pragma unroll
  for (int s = 0; s < 6; ++s) {
    const int bp = s & 1;
    // stage top: consume arrived regs, issue next loads (max lead before drain)
    if (s <= 4) storePair(1 - bp);          // pair s+1 -> other buffer
    if (s <= 3) loadPair(s + 2);            // refill wv
    if (s == 1) loadRaw(1);                 // x factors one stage ahead
    if (s == 3) loadRaw(2);
    if (s == 2 || s == 4) cvtFactors();     // raw arrived at prior barrier

    // compute: K=128 as 4 k-steps of 32 from sW[bp]; A-frags built in regs
#pragma unroll
    for (int ks = 0; ks < 4; ++ks) {
      const int mb = 2 * (s & 1) + (ks >> 1);
      short8 bfr[3];
#pragma unroll
      for (int nt = 0; nt < 3; ++nt)
        bfr[nt] = *(const short8*)&sW[bp][(nt * 16 + row) * SW_COLS + ks * 32 + quad * 8];
#pragma unroll
      for (int mt = 0; mt < 2; ++mt) {
        const float ab = a4[mt][mb] * b2[mt][ks & 1];
        union { unsigned u[4]; short8 s8; } af;
#pragma unroll
        for (int jj = 0; jj < 4; ++jj)
          af.u[jj] = pkbf(ab * cd8[mt][2 * jj], ab * cd8[mt][2 * jj + 1]);
#pragma unroll
        for (int nt = 0; nt < 3; ++nt)
          acc[mt][nt] = __builtin_amdgcn_mfma_f32_16x16x32_bf16(
              af.s8, bfr[nt], acc[mt][nt], 0, 0, 0);
      }
    }
    if (s < 5) __syncthreads();
  }

  // ---- epilogue: D row = quad*4+r (n-local), col = row (po-local) ----
  if (TO_WS) {
#pragma unroll
    for (int mt = 0; mt < 2; ++mt)
#pragma unroll
      for (int r = 0; r < 4; ++r) {
        const int n = wave * 32 + mt * 16 + quad * 4 + r;
#pragma unroll
        for (int nt = 0; nt < 3; ++nt) {
          const int po = nt * 16 + row;
          dst[(size_t)site * 6144 + n * 48 + po] = acc[mt][nt][r];
        }
      }
  } else {
#pragma unroll
    for (int mt = 0; mt < 2; ++mt)
#pragma unroll
      for (int r = 0; r < 4; ++r) {
        const int n = wave * 32 + mt * 16 + quad * 4 + r;
#pragma unroll
        for (int nt = 0; nt < 3; ++nt) {
          const int po = nt * 16 + row;
          const int p = po / 6, o = po - p * 6;
          dst[(size_t)(n * 48 + po) * 961 + site] =
              acc[mt][nt][r] + bias[(p * 961 + site) * 6 + o];
        }
      }
  }
}

// out[f*961 + site] = ws[site*6144 + f] + bias[(p*961+site)*6 + o],  f = n*48+p*6+o
__global__ __launch_bounds__(256, 8)
void ttn_transpose_bias(const float* __restrict__ ws,
                        const float* __restrict__ bias,
                        float* __restrict__ out) {
  __shared__ float tile[32][33];
  const int f0 = blockIdx.x * 32;
  const int s0 = blockIdx.y * 32;
  const int tx = threadIdx.x;       // 0..31
  const int ty = threadIdx.y;       // 0..7

#pragma unroll
  for (int rr = 0; rr < 4; ++rr) {
    const int srow = ty + rr * 8;
    const int site = s0 + srow;
    if (site < 961)
      tile[srow][tx] = ws[(size_t)site * 6144 + f0 + tx];
  }
  __syncthreads();

#pragma unroll
  for (int rr = 0; rr < 4; ++rr) {
    const int fy = ty + rr * 8;
    const int f = f0 + fy;
    const int site = s0 + tx;
    if (site < 961) {
      const int po = f % 48;
      const int p = po / 6, o = po - p * 6;
      out[(size_t)f * 961 + site] = tile[tx][fy] + bias[(p * 961 + site) * 6 + o];
    }
  }
}

extern "C" void kernel_launch(void* const* d_in, const int* in_sizes, int n_in,
                              void* d_out, int out_size, void* d_ws, size_t ws_size,
                              hipStream_t stream) {
  const float* x       = (const float*)d_in[0];
  const float* tensors = (const float*)d_in[1];
  const float* bias    = (const float*)d_in[2];
  float* out           = (float*)d_out;

  const size_t need = (size_t)WS_ELEMS * sizeof(float);
  if (d_ws != nullptr && ws_size >= need) {
    float* ws = (float*)d_ws;
    hipLaunchKernelGGL((ttn_conv_mfma<true>), dim3(961), dim3(256), 0, stream,
                       x, tensors, bias, ws);
    hipLaunchKernelGGL(ttn_transpose_bias, dim3(192, 31), dim3(32, 8), 0, stream,
                       ws, bias, out);
  } else {
    hipLaunchKernelGGL((ttn_conv_mfma<false>), dim3(961), dim3(256), 0, stream,
                       x, tensors, bias, out);
  }
}